// Round 2
// baseline (543.240 us; speedup 1.0000x reference)
//
#include <hip/hip_runtime.h>
#include <math.h>

#define BB 8
#define NN 4096
#define DD 1024
#define HH 256
#define RR 16

// workspace float offsets (all multiples of 16)
#define WS_G       0                 // B*D*R = 131072
#define WS_MU      131072            // B*D
#define WS_DINV    139264            // B*D
#define WS_ALPHA   147456            // B*D
#define WS_LOGDET  155648            // B
#define WS_LOGDSUM 155664            // B
#define WS_MINV    155680            // B*256
#define WS_L       157728            // B*D*R = 131072  (ends at 288800 floats)

// ---------------- kernel A: backbone + heads ----------------
__global__ __launch_bounds__(256) void ka_heads(
    const float* __restrict__ qe, const float* __restrict__ W1, const float* __restrict__ b1,
    const float* __restrict__ Wd, const float* __restrict__ bd,
    const float* __restrict__ WL, const float* __restrict__ bL,
    const float* __restrict__ Wdel, const float* __restrict__ bdel,
    const float* __restrict__ Wa, const float* __restrict__ ba,
    float* __restrict__ ws)
{
    const int b = blockIdx.x >> 3;
    const int slice = blockIdx.x & 7;
    const int tid = threadIdx.x;

    __shared__ float qe_s[DD];
    __shared__ float h_s[HH];
    __shared__ float red_s[256];

    for (int i = tid; i < DD; i += 256) qe_s[i] = qe[b * DD + i];
    __syncthreads();

    // h = relu(qe @ W1 + b1) : each thread one column (H=256)
    {
        float acc = b1[tid];
        #pragma unroll 8
        for (int d = 0; d < DD; ++d) acc = fmaf(qe_s[d], W1[d * HH + tid], acc);
        h_s[tid] = fmaxf(acc, 0.f);
    }
    __syncthreads();

    float logd_part = 0.f;
    const int total = 3 * DD + DD * RR;       // 19456
    const int c0 = slice * 2560;
    int c1 = c0 + 2560; if (c1 > total) c1 = total;

    for (int cc = c0 + tid; cc < c1; cc += 256) {
        if (cc < DD) {
            const int c = cc;
            float acc = bd[c];
            #pragma unroll 8
            for (int r = 0; r < HH; ++r) acc = fmaf(h_s[r], Wd[r * DD + c], acc);
            float ld = fminf(fmaxf(acc, -3.f), 3.f);
            ws[WS_DINV + b * DD + c] = expf(-ld);
            logd_part += ld;
        } else if (cc < 2 * DD) {
            const int c = cc - DD;
            float acc = bdel[c];
            #pragma unroll 8
            for (int r = 0; r < HH; ++r) acc = fmaf(h_s[r], Wdel[r * DD + c], acc);
            ws[WS_MU + b * DD + c] = qe_s[c] + 0.1f * acc;
        } else if (cc < 3 * DD) {
            const int c = cc - 2 * DD;
            float acc = ba[c];
            #pragma unroll 8
            for (int r = 0; r < HH; ++r) acc = fmaf(h_s[r], Wa[r * DD + c], acc);
            ws[WS_ALPHA + b * DD + c] = acc;
        } else {
            const int c = cc - 3 * DD;
            float acc = bL[c];
            #pragma unroll 8
            for (int r = 0; r < HH; ++r) acc = fmaf(h_s[r], WL[r * (DD * RR) + c], acc);
            ws[WS_L + b * (DD * RR) + c] = 0.1f * acc;
        }
    }

    // block-reduce sum(log_d); only slice 0 holds cols 0..1023
    red_s[tid] = logd_part;
    __syncthreads();
    for (int s = 128; s > 0; s >>= 1) {
        if (tid < s) red_s[tid] += red_s[tid + s];
        __syncthreads();
    }
    if (tid == 0 && slice == 0) ws[WS_LOGDSUM + b] = red_s[0];
}

// ---------------- kernel B: M, M^-1 (Gauss-Jordan), logdet, G = Dinv*L ----------------
__global__ __launch_bounds__(256) void kb_solve(float* __restrict__ ws)
{
    const int b = blockIdx.x;
    const int tid = threadIdx.x;

    __shared__ float Mpart[16 * 16 * 16];  // [g][s][u]
    __shared__ float A[16][33];            // augmented [M | I], padded

    const float* Lp = ws + WS_L + (size_t)b * (DD * RR);
    const float* dv = ws + WS_DINV + b * DD;

    // G = dinv[d] * L[d,r]
    for (int idx = tid; idx < DD * RR; idx += 256)
        ws[WS_G + (size_t)b * (DD * RR) + idx] = dv[idx >> 4] * Lp[idx];

    // M partials: thread (g,u): acc[s] = sum_{d = u mod 16} dinv*L[d,g]*L[d,s]
    {
        const int g = tid >> 4, u = tid & 15;
        float acc[16];
        #pragma unroll
        for (int s = 0; s < 16; ++s) acc[s] = 0.f;
        for (int d = u; d < DD; d += 16) {
            const float dvd = dv[d];
            const float lg = Lp[d * 16 + g] * dvd;
            const float4* Lr = (const float4*)(Lp + d * 16);
            float4 l0 = Lr[0], l1 = Lr[1], l2 = Lr[2], l3 = Lr[3];
            float lv[16] = {l0.x, l0.y, l0.z, l0.w, l1.x, l1.y, l1.z, l1.w,
                            l2.x, l2.y, l2.z, l2.w, l3.x, l3.y, l3.z, l3.w};
            #pragma unroll
            for (int s = 0; s < 16; ++s) acc[s] = fmaf(lg, lv[s], acc[s]);
        }
        #pragma unroll
        for (int s = 0; s < 16; ++s) Mpart[g * 256 + s * 16 + u] = acc[s];
    }
    __syncthreads();

    const int i = tid >> 4, j = tid & 15;
    {
        float m = (i == j) ? 1.f : 0.f;
        #pragma unroll
        for (int u = 0; u < 16; ++u) m += Mpart[i * 256 + j * 16 + u];
        A[i][j] = m;
        A[i][j + 16] = (i == j) ? 1.f : 0.f;
    }
    __syncthreads();

    float logdetM = 0.f;   // meaningful on tid 0 only
    for (int k = 0; k < 16; ++k) {
        const float piv = A[k][k];
        if (tid == 0) logdetM += logf(piv);
        __syncthreads();
        if (i == k) {
            const float rinv = 1.f / piv;
            A[i][j] *= rinv;
            A[i][j + 16] *= rinv;
        }
        __syncthreads();
        const float f = (i == k) ? 0.f : A[i][k];
        __syncthreads();
        if (i != k) {
            A[i][j]      = fmaf(-f, A[k][j],      A[i][j]);
            A[i][j + 16] = fmaf(-f, A[k][j + 16], A[i][j + 16]);
        }
        __syncthreads();
    }

    ws[WS_MINV + b * 256 + i * 16 + j] = A[i][j + 16];
    if (tid == 0) ws[WS_LOGDET + b] = ws[WS_LOGDSUM + b] + logdetM;
}

// ---------------- kernel C: main streaming pass ----------------
__global__ __launch_bounds__(256, 2) void kc_main(
    const float* __restrict__ ctx, const float* __restrict__ ws, float* __restrict__ out)
{
    const int bid = blockIdx.x;          // 2048 blocks
    const int b = bid >> 8;              // 256 tiles per batch
    const int tile = bid & 255;
    const int wave = threadIdx.x >> 6;
    const int lane = threadIdx.x & 63;
    const int n0 = tile * 16 + wave * 4; // 4 rows per wave

    const float4* G4  = (const float4*)(ws + WS_G + (size_t)b * (DD * RR));
    const float4* mu4 = (const float4*)(ws + WS_MU + b * DD);
    const float4* dv4 = (const float4*)(ws + WS_DINV + b * DD);
    const float4* al4 = (const float4*)(ws + WS_ALPHA + b * DD);
    const float4* ctx4 = (const float4*)(ctx + ((size_t)(b * NN + n0)) * DD);

    float g[4][16];
    float md[4], aa[4];
    #pragma unroll
    for (int i = 0; i < 4; ++i) {
        md[i] = 0.f; aa[i] = 0.f;
        #pragma unroll
        for (int r = 0; r < 16; ++r) g[i][r] = 0.f;
    }

    #pragma unroll
    for (int step = 0; step < 4; ++step) {
        const int fi = step * 64 + lane;      // float4 index within D
        float4 mv = mu4[fi], dvv = dv4[fi], av = al4[fi];
        float4 c0 = ctx4[0 * (DD / 4) + fi];
        float4 c1 = ctx4[1 * (DD / 4) + fi];
        float4 c2 = ctx4[2 * (DD / 4) + fi];
        float4 c3 = ctx4[3 * (DD / 4) + fi];
        const float mva[4] = {mv.x, mv.y, mv.z, mv.w};
        const float dva[4] = {dvv.x, dvv.y, dvv.z, dvv.w};
        const float ava[4] = {av.x, av.y, av.z, av.w};
        const float ca[4][4] = {{c0.x, c0.y, c0.z, c0.w},
                                {c1.x, c1.y, c1.z, c1.w},
                                {c2.x, c2.y, c2.z, c2.w},
                                {c3.x, c3.y, c3.z, c3.w}};
        #pragma unroll
        for (int j = 0; j < 4; ++j) {
            const int d = fi * 4 + j;
            float4 q0 = G4[d * 4 + 0], q1 = G4[d * 4 + 1];
            float4 q2 = G4[d * 4 + 2], q3 = G4[d * 4 + 3];
            const float Gv[16] = {q0.x, q0.y, q0.z, q0.w, q1.x, q1.y, q1.z, q1.w,
                                  q2.x, q2.y, q2.z, q2.w, q3.x, q3.y, q3.z, q3.w};
            #pragma unroll
            for (int i = 0; i < 4; ++i) {
                const float diff = ca[i][j] - mva[j];
                const float t = diff * dva[j];
                md[i] = fmaf(t, diff, md[i]);
                aa[i] = fmaf(ava[j], diff, aa[i]);
                #pragma unroll
                for (int r = 0; r < 16; ++r) g[i][r] = fmaf(Gv[r], diff, g[i][r]);
            }
        }
    }

    // fold-halving transpose-reduce: 64 slots (row i, r) across 64 lanes.
    // End state: lane l holds total for slot l (row = l>>4, r = l&15).
    float v[64];
    #pragma unroll
    for (int i = 0; i < 4; ++i)
        #pragma unroll
        for (int r = 0; r < 16; ++r) v[i * 16 + r] = g[i][r];

    #pragma unroll
    for (int s6 = 0; s6 < 6; ++s6) {
        const int m = 1 << s6;
        const int half = 32 >> s6;
        const bool up = (lane & m) != 0;
        #pragma unroll
        for (int ii = 0; ii < half; ++ii) {
            float x0 = v[2 * ii], x1 = v[2 * ii + 1];
            float y0 = __shfl_xor(x0, m, 64);
            float y1 = __shfl_xor(x1, m, 64);
            v[ii] = up ? (x1 + y1) : (x0 + y0);
        }
    }
    const float w = v[0];

    // full butterfly for md/aa (every lane gets all 4 row sums)
    #pragma unroll
    for (int m = 1; m < 64; m <<= 1) {
        #pragma unroll
        for (int i = 0; i < 4; ++i) {
            md[i] += __shfl_xor(md[i], m, 64);
            aa[i] += __shfl_xor(aa[i], m, 64);
        }
    }

    // correction = w^T Minv w per row (16-lane group holds the 16 w components)
    const int r = lane & 15;
    const int rowbase = lane & 48;
    const float* Minv = ws + WS_MINV + b * 256 + r * 16;
    float y = 0.f;
    #pragma unroll
    for (int s = 0; s < 16; ++s) y = fmaf(Minv[s], __shfl(w, rowbase + s, 64), y);
    float corr = w * y;
    corr += __shfl_xor(corr, 1, 64);
    corr += __shfl_xor(corr, 2, 64);
    corr += __shfl_xor(corr, 4, 64);
    corr += __shfl_xor(corr, 8, 64);

    const float ld = ws[WS_LOGDET + b];
    if ((lane & 15) == 0) {
        const int i = lane >> 4;
        const float mdv = (i & 2) ? ((i & 1) ? md[3] : md[2]) : ((i & 1) ? md[1] : md[0]);
        const float aav = (i & 2) ? ((i & 1) ? aa[3] : aa[2]) : ((i & 1) ? aa[1] : aa[0]);
        const float lsig = fminf(aav, 0.f) - log1pf(expf(-fabsf(aav)));
        out[(size_t)b * NN + n0 + i] = -0.5f * (mdv - corr + ld) + lsig;
    }
}

extern "C" void kernel_launch(void* const* d_in, const int* in_sizes, int n_in,
                              void* d_out, int out_size, void* d_ws, size_t ws_size,
                              hipStream_t stream)
{
    const float* qe   = (const float*)d_in[0];
    const float* ctx  = (const float*)d_in[1];
    const float* W1   = (const float*)d_in[2];
    const float* b1   = (const float*)d_in[3];
    const float* Wd   = (const float*)d_in[4];
    const float* bd   = (const float*)d_in[5];
    const float* WL   = (const float*)d_in[6];
    const float* bL   = (const float*)d_in[7];
    const float* Wdel = (const float*)d_in[8];
    const float* bdel = (const float*)d_in[9];
    const float* Wa   = (const float*)d_in[10];
    const float* ba   = (const float*)d_in[11];
    float* out = (float*)d_out;
    float* ws  = (float*)d_ws;

    ka_heads<<<64, 256, 0, stream>>>(qe, W1, b1, Wd, bd, WL, bL, Wdel, bdel, Wa, ba, ws);
    kb_solve<<<8, 256, 0, stream>>>(ws);
    kc_main<<<2048, 256, 0, stream>>>(ctx, ws, out);
}

// Round 4
// 348.038 us; speedup vs baseline: 1.5609x; 1.5609x over previous
//
#include <hip/hip_runtime.h>
#include <math.h>

#define BB 8
#define NN 4096
#define DD 1024
#define HH 256
#define RR 16

// workspace float offsets
#define WS_GT      0                   // B*R*D = 131072   (G_t[b][r][d])
#define WS_MU      131072              // B*D   = 8192
#define WS_DINV    139264              // B*D
#define WS_ALPHA   147456              // B*D
#define WS_LOGD    155648              // B*D
#define WS_H       163840              // B*H   = 2048
#define WS_LOGDET  165888              // 16
#define WS_MINV    165904              // B*256 = 2048
#define WS_L       167952              // B*D*R = 131072  (ends 299024 floats ~1.2MB)

// ---------------- kernel A1: h = relu(qe @ W1 + b1) ----------------
__global__ __launch_bounds__(256) void ka1_h(
    const float* __restrict__ qe, const float* __restrict__ W1,
    const float* __restrict__ b1, float* __restrict__ ws)
{
    const int b = blockIdx.x;
    const int c = threadIdx.x;
    __shared__ float qe_s[DD];
    for (int i = c; i < DD; i += 256) qe_s[i] = qe[b * DD + i];
    __syncthreads();
    float a0 = 0.f, a1 = 0.f, a2 = 0.f, a3 = 0.f;
    for (int d = 0; d < DD; d += 4) {
        a0 = fmaf(qe_s[d + 0], W1[(d + 0) * HH + c], a0);
        a1 = fmaf(qe_s[d + 1], W1[(d + 1) * HH + c], a1);
        a2 = fmaf(qe_s[d + 2], W1[(d + 2) * HH + c], a2);
        a3 = fmaf(qe_s[d + 3], W1[(d + 3) * HH + c], a3);
    }
    ws[WS_H + b * HH + c] = fmaxf((a0 + a1) + (a2 + a3) + b1[c], 0.f);
}

// ---------------- kernel A2: all heads, one column for all 8 batches ----------------
__global__ __launch_bounds__(256) void ka2_heads(
    const float* __restrict__ qe,
    const float* __restrict__ Wd, const float* __restrict__ bd,
    const float* __restrict__ WL, const float* __restrict__ bL,
    const float* __restrict__ Wdel, const float* __restrict__ bdel,
    const float* __restrict__ Wa, const float* __restrict__ ba,
    float* __restrict__ ws)
{
    __shared__ float h_s[BB * HH];   // 8 KB
    const int tid = threadIdx.x;
    for (int i = tid; i < BB * HH; i += 256) h_s[i] = ws[WS_H + i];
    __syncthreads();

    const int blk = blockIdx.x;      // 0..75
    int mode, c;
    const float* W; const float* bias;
    if (blk < 4)       { mode = 0; c = blk * 256 + tid;        W = Wd;   bias = bd;   }
    else if (blk < 8)  { mode = 1; c = (blk - 4) * 256 + tid;  W = Wdel; bias = bdel; }
    else if (blk < 12) { mode = 2; c = (blk - 8) * 256 + tid;  W = Wa;   bias = ba;   }
    else               { mode = 3; c = (blk - 12) * 256 + tid; W = WL;   bias = bL;   }
    const int ld = (mode == 3) ? (DD * RR) : DD;

    float acc[8];
    const float bc = bias[c];
    #pragma unroll
    for (int b = 0; b < 8; ++b) acc[b] = bc;

    #pragma unroll 4
    for (int r = 0; r < HH; ++r) {
        const float w = W[r * ld + c];
        #pragma unroll
        for (int b = 0; b < 8; ++b) acc[b] = fmaf(h_s[b * HH + r], w, acc[b]);
    }

    if (mode == 0) {
        #pragma unroll
        for (int b = 0; b < 8; ++b) {
            const float ldv = fminf(fmaxf(acc[b], -3.f), 3.f);
            ws[WS_LOGD + b * DD + c] = ldv;
            ws[WS_DINV + b * DD + c] = expf(-ldv);
        }
    } else if (mode == 1) {
        #pragma unroll
        for (int b = 0; b < 8; ++b)
            ws[WS_MU + b * DD + c] = qe[b * DD + c] + 0.1f * acc[b];
    } else if (mode == 2) {
        #pragma unroll
        for (int b = 0; b < 8; ++b) ws[WS_ALPHA + b * DD + c] = acc[b];
    } else {
        #pragma unroll
        for (int b = 0; b < 8; ++b) ws[WS_L + b * DD * RR + c] = 0.1f * acc[b];
    }
}

// ---------------- kernel G: G_t[b][r][d] = dinv[b][d] * L[b][d][r] ----------------
__global__ __launch_bounds__(256) void kg_gt(float* __restrict__ ws)
{
    const int idx = blockIdx.x * 256 + threadIdx.x;   // 512 blocks -> B*R*D
    const int d = idx & (DD - 1);
    const int r = (idx >> 10) & (RR - 1);
    const int b = idx >> 14;
    ws[WS_GT + idx] = ws[WS_DINV + b * DD + d] * ws[WS_L + (b * DD + d) * RR + r];
}

// ---------------- kernel B: M, M^-1 (Gauss-Jordan), logdet ----------------
__global__ __launch_bounds__(256) void kb_solve(float* __restrict__ ws)
{
    const int b = blockIdx.x;
    const int tid = threadIdx.x;

    __shared__ float Mpart[16 * 16 * 16];  // [g][s][u]
    __shared__ float A[16][33];
    __shared__ float red_s[256];

    const float* Lp = ws + WS_L + (size_t)b * (DD * RR);
    const float* Gt = ws + WS_GT + (size_t)b * (RR * DD);

    // sum(log_d)
    float lsum = 0.f;
    for (int i = tid; i < DD; i += 256) lsum += ws[WS_LOGD + b * DD + i];
    red_s[tid] = lsum;
    __syncthreads();
    for (int s = 128; s > 0; s >>= 1) {
        if (tid < s) red_s[tid] += red_s[tid + s];
        __syncthreads();
    }
    const float logdsum = red_s[0];
    __syncthreads();

    // M partials: thread (g,u): acc[s] = sum_{d ≡ u (16)} G_t[g][d] * L[d][s]
    {
        const int g = tid >> 4, u = tid & 15;
        float acc[16];
        #pragma unroll
        for (int s = 0; s < 16; ++s) acc[s] = 0.f;
        for (int d = u; d < DD; d += 16) {
            const float lg = Gt[g * DD + d];
            const float4* Lr = (const float4*)(Lp + d * 16);
            float4 l0 = Lr[0], l1 = Lr[1], l2 = Lr[2], l3 = Lr[3];
            const float lv[16] = {l0.x, l0.y, l0.z, l0.w, l1.x, l1.y, l1.z, l1.w,
                                  l2.x, l2.y, l2.z, l2.w, l3.x, l3.y, l3.z, l3.w};
            #pragma unroll
            for (int s = 0; s < 16; ++s) acc[s] = fmaf(lg, lv[s], acc[s]);
        }
        #pragma unroll
        for (int s = 0; s < 16; ++s) Mpart[g * 256 + s * 16 + u] = acc[s];
    }
    __syncthreads();

    const int i = tid >> 4, j = tid & 15;
    {
        float m = (i == j) ? 1.f : 0.f;
        #pragma unroll
        for (int u = 0; u < 16; ++u) m += Mpart[i * 256 + j * 16 + u];
        A[i][j] = m;
        A[i][j + 16] = (i == j) ? 1.f : 0.f;
    }
    __syncthreads();

    float logdetM = 0.f;
    for (int k = 0; k < 16; ++k) {
        const float piv = A[k][k];
        if (tid == 0) logdetM += logf(piv);
        __syncthreads();
        if (i == k) {
            const float rinv = 1.f / piv;
            A[i][j] *= rinv;
            A[i][j + 16] *= rinv;
        }
        __syncthreads();
        const float f = (i == k) ? 0.f : A[i][k];
        __syncthreads();
        if (i != k) {
            A[i][j]      = fmaf(-f, A[k][j],      A[i][j]);
            A[i][j + 16] = fmaf(-f, A[k][j + 16], A[i][j + 16]);
        }
        __syncthreads();
    }

    ws[WS_MINV + b * 256 + i * 16 + j] = A[i][j + 16];
    if (tid == 0) ws[WS_LOGDET + b] = logdsum + logdetM;
}

// ---------------- kernel C: main streaming pass ----------------
__global__ __launch_bounds__(256, 2) void kc_main(
    const float* __restrict__ ctx, const float* __restrict__ ws, float* __restrict__ out)
{
    const int bid = blockIdx.x;          // 2048 blocks
    const int b = bid >> 8;
    const int tile = bid & 255;
    const int wave = threadIdx.x >> 6;
    const int lane = threadIdx.x & 63;
    const int n0 = tile * 16 + wave * 4;

    const float4* Gt4 = (const float4*)(ws + WS_GT + (size_t)b * (RR * DD)); // row r at Gt4[r*256 + fi]
    const float4* mu4 = (const float4*)(ws + WS_MU + b * DD);
    const float4* dv4 = (const float4*)(ws + WS_DINV + b * DD);
    const float4* al4 = (const float4*)(ws + WS_ALPHA + b * DD);
    const float4* ctx4 = (const float4*)(ctx + ((size_t)(b * NN + n0)) * DD);

    float g[4][16];
    float md[4], aa[4];
    #pragma unroll
    for (int i = 0; i < 4; ++i) {
        md[i] = 0.f; aa[i] = 0.f;
        #pragma unroll
        for (int r = 0; r < 16; ++r) g[i][r] = 0.f;
    }

    #pragma unroll
    for (int step = 0; step < 4; ++step) {
        const int fi = step * 64 + lane;      // float4 index within D
        const float4 mv = mu4[fi], dvv = dv4[fi], av = al4[fi];
        const float4 c0 = ctx4[0 * (DD / 4) + fi];
        const float4 c1 = ctx4[1 * (DD / 4) + fi];
        const float4 c2 = ctx4[2 * (DD / 4) + fi];
        const float4 c3 = ctx4[3 * (DD / 4) + fi];

        float diff[4][4];
        diff[0][0] = c0.x - mv.x; diff[0][1] = c0.y - mv.y; diff[0][2] = c0.z - mv.z; diff[0][3] = c0.w - mv.w;
        diff[1][0] = c1.x - mv.x; diff[1][1] = c1.y - mv.y; diff[1][2] = c1.z - mv.z; diff[1][3] = c1.w - mv.w;
        diff[2][0] = c2.x - mv.x; diff[2][1] = c2.y - mv.y; diff[2][2] = c2.z - mv.z; diff[2][3] = c2.w - mv.w;
        diff[3][0] = c3.x - mv.x; diff[3][1] = c3.y - mv.y; diff[3][2] = c3.z - mv.z; diff[3][3] = c3.w - mv.w;

        const float dva[4] = {dvv.x, dvv.y, dvv.z, dvv.w};
        const float ava[4] = {av.x, av.y, av.z, av.w};
        #pragma unroll
        for (int i = 0; i < 4; ++i) {
            #pragma unroll
            for (int j = 0; j < 4; ++j) {
                md[i] = fmaf(diff[i][j] * dva[j], diff[i][j], md[i]);
                aa[i] = fmaf(ava[j], diff[i][j], aa[i]);
            }
        }

        #pragma unroll
        for (int r = 0; r < 16; ++r) {
            const float4 gt = Gt4[r * 256 + fi];
            #pragma unroll
            for (int i = 0; i < 4; ++i) {
                g[i][r] = fmaf(gt.x, diff[i][0], g[i][r]);
                g[i][r] = fmaf(gt.y, diff[i][1], g[i][r]);
                g[i][r] = fmaf(gt.z, diff[i][2], g[i][r]);
                g[i][r] = fmaf(gt.w, diff[i][3], g[i][r]);
            }
        }
    }

    // fold-halving transpose-reduce: 64 slots (row i, r) across 64 lanes.
    float v[64];
    #pragma unroll
    for (int i = 0; i < 4; ++i)
        #pragma unroll
        for (int r = 0; r < 16; ++r) v[i * 16 + r] = g[i][r];

    #pragma unroll
    for (int s6 = 0; s6 < 6; ++s6) {
        const int m = 1 << s6;
        const int half = 32 >> s6;
        const bool up = (lane & m) != 0;
        #pragma unroll
        for (int ii = 0; ii < half; ++ii) {
            float x0 = v[2 * ii], x1 = v[2 * ii + 1];
            float y0 = __shfl_xor(x0, m, 64);
            float y1 = __shfl_xor(x1, m, 64);
            v[ii] = up ? (x1 + y1) : (x0 + y0);
        }
    }
    const float w = v[0];

    #pragma unroll
    for (int m = 1; m < 64; m <<= 1) {
        #pragma unroll
        for (int i = 0; i < 4; ++i) {
            md[i] += __shfl_xor(md[i], m, 64);
            aa[i] += __shfl_xor(aa[i], m, 64);
        }
    }

    const int r = lane & 15;
    const int rowbase = lane & 48;
    const float* Minv = ws + WS_MINV + b * 256 + r * 16;
    float y = 0.f;
    #pragma unroll
    for (int s = 0; s < 16; ++s) y = fmaf(Minv[s], __shfl(w, rowbase + s, 64), y);
    float corr = w * y;
    corr += __shfl_xor(corr, 1, 64);
    corr += __shfl_xor(corr, 2, 64);
    corr += __shfl_xor(corr, 4, 64);
    corr += __shfl_xor(corr, 8, 64);

    const float ld = ws[WS_LOGDET + b];
    if ((lane & 15) == 0) {
        const int i = lane >> 4;
        const float mdv = (i & 2) ? ((i & 1) ? md[3] : md[2]) : ((i & 1) ? md[1] : md[0]);
        const float aav = (i & 2) ? ((i & 1) ? aa[3] : aa[2]) : ((i & 1) ? aa[1] : aa[0]);
        const float lsig = fminf(aav, 0.f) - log1pf(expf(-fabsf(aav)));
        out[(size_t)b * NN + n0 + i] = -0.5f * (mdv - corr + ld) + lsig;
    }
}

extern "C" void kernel_launch(void* const* d_in, const int* in_sizes, int n_in,
                              void* d_out, int out_size, void* d_ws, size_t ws_size,
                              hipStream_t stream)
{
    const float* qe   = (const float*)d_in[0];
    const float* ctx  = (const float*)d_in[1];
    const float* W1   = (const float*)d_in[2];
    const float* b1   = (const float*)d_in[3];
    const float* Wd   = (const float*)d_in[4];
    const float* bd   = (const float*)d_in[5];
    const float* WL   = (const float*)d_in[6];
    const float* bL   = (const float*)d_in[7];
    const float* Wdel = (const float*)d_in[8];
    const float* bdel = (const float*)d_in[9];
    const float* Wa   = (const float*)d_in[10];
    const float* ba   = (const float*)d_in[11];
    float* out = (float*)d_out;
    float* ws  = (float*)d_ws;

    ka1_h<<<8, 256, 0, stream>>>(qe, W1, b1, ws);
    ka2_heads<<<76, 256, 0, stream>>>(qe, Wd, bd, WL, bL, Wdel, bdel, Wa, ba, ws);
    kg_gt<<<512, 256, 0, stream>>>(ws);
    kb_solve<<<8, 256, 0, stream>>>(ws);
    kc_main<<<2048, 256, 0, stream>>>(ctx, ws, out);
}

// Round 5
// 326.191 us; speedup vs baseline: 1.6654x; 1.0670x over previous
//
#include <hip/hip_runtime.h>
#include <math.h>

#define BB 8
#define NN 4096
#define DD 1024
#define HH 256
#define RR 16

// workspace float offsets
#define WS_GT      0                   // B*R*D = 131072   (G_t[b][r][d])
#define WS_MU      131072              // B*D   = 8192
#define WS_DINV    139264              // B*D
#define WS_ALPHA   147456              // B*D
#define WS_HP      155648              // B*4*H = 8192   (partial h)
#define WS_LDP     163840              // 16*8 = 128     (logd partials per mode0-block)
#define WS_M       163968              // B*256 = 2048
#define WS_MINV    166016              // B*256 = 2048
#define WS_LOGDET  168064              // 16
#define WS_L       168080              // B*D*R = 131072  (ends 299152 floats ~1.2MB)

// ---------------- kernel A1: partial h (split-D) ----------------
__global__ __launch_bounds__(256) void ka1_h(
    const float* __restrict__ qe, const float* __restrict__ W1, float* __restrict__ ws)
{
    const int b = blockIdx.x >> 2;
    const int sl = blockIdx.x & 3;          // D-slice of 256
    const int c = threadIdx.x;
    __shared__ float qe_s[256];
    qe_s[c] = qe[b * DD + sl * 256 + c];
    __syncthreads();
    float a0 = 0.f, a1 = 0.f, a2 = 0.f, a3 = 0.f;
    const float* W1p = W1 + (sl * 256) * HH;
    for (int dl = 0; dl < 256; dl += 4) {
        a0 = fmaf(qe_s[dl + 0], W1p[(dl + 0) * HH + c], a0);
        a1 = fmaf(qe_s[dl + 1], W1p[(dl + 1) * HH + c], a1);
        a2 = fmaf(qe_s[dl + 2], W1p[(dl + 2) * HH + c], a2);
        a3 = fmaf(qe_s[dl + 3], W1p[(dl + 3) * HH + c], a3);
    }
    ws[WS_HP + (b * 4 + sl) * HH + c] = (a0 + a1) + (a2 + a3);
}

// ---------------- kernel A2: all heads; 64 cols/block, 4-way split-H ----------------
// blk 0..15: Wd | 16..31: Wdel | 32..47: Wa | 48..303: WL
__global__ __launch_bounds__(256) void ka2_heads(
    const float* __restrict__ qe, const float* __restrict__ b1,
    const float* __restrict__ Wd, const float* __restrict__ bd,
    const float* __restrict__ WL, const float* __restrict__ bL,
    const float* __restrict__ Wdel, const float* __restrict__ bdel,
    const float* __restrict__ Wa, const float* __restrict__ ba,
    float* __restrict__ ws)
{
    __shared__ float h_s[BB * HH];    // 8 KB
    __shared__ float red[4][512];     // 8 KB
    const int tid = threadIdx.x;

    // finalize h from partials (bias + relu)
    for (int i = tid; i < BB * HH; i += 256) {
        const int bb = i >> 8, c = i & 255;
        const float v = ws[WS_HP + (bb * 4 + 0) * HH + c] + ws[WS_HP + (bb * 4 + 1) * HH + c]
                      + ws[WS_HP + (bb * 4 + 2) * HH + c] + ws[WS_HP + (bb * 4 + 3) * HH + c]
                      + b1[c];
        h_s[i] = fmaxf(v, 0.f);
    }
    __syncthreads();

    const int blk = blockIdx.x;
    const int lane = tid & 63;
    const int u = tid >> 6;

    int mode; const float* W; const float* bias; int base;
    if (blk < 16)       { mode = 0; W = Wd;   bias = bd;   base = 0;  }
    else if (blk < 32)  { mode = 1; W = Wdel; bias = bdel; base = 16; }
    else if (blk < 48)  { mode = 2; W = Wa;   bias = ba;   base = 32; }
    else                { mode = 3; W = WL;   bias = bL;   base = 48; }
    const int ld = (mode == 3) ? (DD * RR) : DD;
    const int cc = (blk - base) * 64 + lane;     // column within this matrix

    float acc[8];
    #pragma unroll
    for (int b = 0; b < 8; ++b) acc[b] = 0.f;

    #pragma unroll 4
    for (int rr = 0; rr < 64; ++rr) {
        const int r = u * 64 + rr;
        const float wv = W[r * ld + cc];
        #pragma unroll
        for (int b = 0; b < 8; ++b) acc[b] = fmaf(h_s[b * HH + r], wv, acc[b]);
    }
    #pragma unroll
    for (int b = 0; b < 8; ++b) red[u][lane * 8 + b] = acc[b];
    __syncthreads();

    for (int e = tid; e < 512; e += 256) {
        const int cl = e >> 3, bb = e & 7;
        const int cm = (blk - base) * 64 + cl;   // col within matrix
        float s = red[0][e] + red[1][e] + red[2][e] + red[3][e] + bias[cm];
        if (mode == 0) {
            const float ldv = fminf(fmaxf(s, -3.f), 3.f);
            ws[WS_DINV + bb * DD + cm] = expf(-ldv);
            red[0][e] = ldv;                     // stash for logd partial
        } else if (mode == 1) {
            ws[WS_MU + bb * DD + cm] = qe[bb * DD + cm] + 0.1f * s;
        } else if (mode == 2) {
            ws[WS_ALPHA + bb * DD + cm] = s;
        } else {
            ws[WS_L + bb * (DD * RR) + cm] = 0.1f * s;
        }
    }
    if (mode == 0) {
        __syncthreads();
        if (tid < 8) {
            float s = 0.f;
            for (int cl = 0; cl < 64; ++cl) s += red[0][cl * 8 + tid];
            ws[WS_LDP + blk * 8 + tid] = s;
        }
    }
}

// ---------------- kernel G: G_t[b][r][d] = dinv[b][d] * L[b][d][r] ----------------
__global__ __launch_bounds__(256) void kg_gt(float* __restrict__ ws)
{
    const int idx = blockIdx.x * 256 + threadIdx.x;   // 512 blocks -> B*R*D
    const int d = idx & (DD - 1);
    const int r = (idx >> 10) & (RR - 1);
    const int b = idx >> 14;
    ws[WS_GT + idx] = ws[WS_DINV + b * DD + d] * ws[WS_L + (b * DD + d) * RR + r];
}

// ---------------- kernel M: M[b][g][s] = I + sum_d Gt[g][d] L[d][s] ----------------
__global__ __launch_bounds__(256) void kM(float* __restrict__ ws)
{
    const int b = blockIdx.x >> 4;
    const int g = blockIdx.x & 15;
    const int tid = threadIdx.x;
    const int s = tid & 15, dg = tid >> 4;

    const float* Gt = ws + WS_GT + (size_t)b * (RR * DD) + g * DD;
    const float* Lp = ws + WS_L + (size_t)b * (DD * RR);

    float acc = 0.f;
    #pragma unroll 4
    for (int k = 0; k < 64; ++k) {
        const int d = dg * 64 + k;
        acc = fmaf(Gt[d], Lp[d * 16 + s], acc);
    }
    __shared__ float red2[16][17];
    red2[dg][s] = acc;
    __syncthreads();
    if (tid < 16) {
        float m = (tid == g) ? 1.f : 0.f;
        #pragma unroll
        for (int d2 = 0; d2 < 16; ++d2) m += red2[d2][tid];
        ws[WS_M + b * 256 + g * 16 + tid] = m;
    }
}

// ---------------- kernel GJ: invert M, logdet ----------------
__global__ __launch_bounds__(256) void kGJ(float* __restrict__ ws)
{
    const int b = blockIdx.x;
    const int tid = threadIdx.x;
    const int i = tid >> 4, j = tid & 15;
    __shared__ float A[16][33];

    A[i][j] = ws[WS_M + b * 256 + i * 16 + j];
    A[i][j + 16] = (i == j) ? 1.f : 0.f;
    __syncthreads();

    float logdetM = 0.f;
    for (int k = 0; k < 16; ++k) {
        const float piv = A[k][k];
        if (tid == 0) logdetM += logf(piv);
        __syncthreads();
        if (i == k) {
            const float rinv = 1.f / piv;
            A[i][j] *= rinv;
            A[i][j + 16] *= rinv;
        }
        __syncthreads();
        const float f = (i == k) ? 0.f : A[i][k];
        __syncthreads();
        if (i != k) {
            A[i][j]      = fmaf(-f, A[k][j],      A[i][j]);
            A[i][j + 16] = fmaf(-f, A[k][j + 16], A[i][j + 16]);
        }
        __syncthreads();
    }
    ws[WS_MINV + b * 256 + i * 16 + j] = A[i][j + 16];
    if (tid == 0) {
        float lds = 0.f;
        for (int k = 0; k < 16; ++k) lds += ws[WS_LDP + k * 8 + b];
        ws[WS_LOGDET + b] = lds + logdetM;
    }
}

// ---------------- kernel C: main streaming pass (Gt in LDS) ----------------
__global__ __launch_bounds__(512, 4) void kc_main(
    const float* __restrict__ ctx, const float* __restrict__ ws, float* __restrict__ out)
{
    const int bid = blockIdx.x;          // 1024 blocks
    const int b = bid >> 7;              // 128 tiles of 32 rows per batch
    const int tile = bid & 127;
    const int wave = threadIdx.x >> 6;   // 0..7
    const int lane = threadIdx.x & 63;
    const int n0 = tile * 32 + wave * 4;

    __shared__ float gt_s[RR * DD];      // 64 KB
    {
        float4* gs4 = (float4*)gt_s;
        const float4* Gt4g = (const float4*)(ws + WS_GT + (size_t)b * (RR * DD));
        for (int i = threadIdx.x; i < RR * DD / 4; i += 512) gs4[i] = Gt4g[i];
    }
    __syncthreads();
    const float4* gs4 = (const float4*)gt_s;

    const float4* mu4 = (const float4*)(ws + WS_MU + b * DD);
    const float4* dv4 = (const float4*)(ws + WS_DINV + b * DD);
    const float4* al4 = (const float4*)(ws + WS_ALPHA + b * DD);
    const float4* ctx4 = (const float4*)(ctx + ((size_t)(b * NN + n0)) * DD);

    float g[4][16];
    float md[4], aa[4];
    #pragma unroll
    for (int i = 0; i < 4; ++i) {
        md[i] = 0.f; aa[i] = 0.f;
        #pragma unroll
        for (int r = 0; r < 16; ++r) g[i][r] = 0.f;
    }

    #pragma unroll
    for (int step = 0; step < 4; ++step) {
        const int fi = step * 64 + lane;      // float4 index within D
        const float4 mv = mu4[fi], dvv = dv4[fi], av = al4[fi];
        const float4 c0 = ctx4[0 * (DD / 4) + fi];
        const float4 c1 = ctx4[1 * (DD / 4) + fi];
        const float4 c2 = ctx4[2 * (DD / 4) + fi];
        const float4 c3 = ctx4[3 * (DD / 4) + fi];

        float diff[4][4];
        diff[0][0] = c0.x - mv.x; diff[0][1] = c0.y - mv.y; diff[0][2] = c0.z - mv.z; diff[0][3] = c0.w - mv.w;
        diff[1][0] = c1.x - mv.x; diff[1][1] = c1.y - mv.y; diff[1][2] = c1.z - mv.z; diff[1][3] = c1.w - mv.w;
        diff[2][0] = c2.x - mv.x; diff[2][1] = c2.y - mv.y; diff[2][2] = c2.z - mv.z; diff[2][3] = c2.w - mv.w;
        diff[3][0] = c3.x - mv.x; diff[3][1] = c3.y - mv.y; diff[3][2] = c3.z - mv.z; diff[3][3] = c3.w - mv.w;

        const float dva[4] = {dvv.x, dvv.y, dvv.z, dvv.w};
        const float ava[4] = {av.x, av.y, av.z, av.w};
        #pragma unroll
        for (int i = 0; i < 4; ++i) {
            #pragma unroll
            for (int j = 0; j < 4; ++j) {
                md[i] = fmaf(diff[i][j] * dva[j], diff[i][j], md[i]);
                aa[i] = fmaf(ava[j], diff[i][j], aa[i]);
            }
        }

        #pragma unroll
        for (int r = 0; r < 16; ++r) {
            const float4 gt = gs4[r * 256 + fi];
            #pragma unroll
            for (int i = 0; i < 4; ++i) {
                g[i][r] = fmaf(gt.x, diff[i][0], g[i][r]);
                g[i][r] = fmaf(gt.y, diff[i][1], g[i][r]);
                g[i][r] = fmaf(gt.z, diff[i][2], g[i][r]);
                g[i][r] = fmaf(gt.w, diff[i][3], g[i][r]);
            }
        }
    }

    // fold-halving transpose-reduce: 64 slots (row i, r) across 64 lanes.
    float v[64];
    #pragma unroll
    for (int i = 0; i < 4; ++i)
        #pragma unroll
        for (int r = 0; r < 16; ++r) v[i * 16 + r] = g[i][r];

    #pragma unroll
    for (int s6 = 0; s6 < 6; ++s6) {
        const int m = 1 << s6;
        const int half = 32 >> s6;
        const bool up = (lane & m) != 0;
        #pragma unroll
        for (int ii = 0; ii < half; ++ii) {
            float x0 = v[2 * ii], x1 = v[2 * ii + 1];
            float y0 = __shfl_xor(x0, m, 64);
            float y1 = __shfl_xor(x1, m, 64);
            v[ii] = up ? (x1 + y1) : (x0 + y0);
        }
    }
    const float w = v[0];

    #pragma unroll
    for (int m = 1; m < 64; m <<= 1) {
        #pragma unroll
        for (int i = 0; i < 4; ++i) {
            md[i] += __shfl_xor(md[i], m, 64);
            aa[i] += __shfl_xor(aa[i], m, 64);
        }
    }

    const int r = lane & 15;
    const int rowbase = lane & 48;
    const float* Minv = ws + WS_MINV + b * 256 + r * 16;
    float y = 0.f;
    #pragma unroll
    for (int s = 0; s < 16; ++s) y = fmaf(Minv[s], __shfl(w, rowbase + s, 64), y);
    float corr = w * y;
    corr += __shfl_xor(corr, 1, 64);
    corr += __shfl_xor(corr, 2, 64);
    corr += __shfl_xor(corr, 4, 64);
    corr += __shfl_xor(corr, 8, 64);

    const float ld = ws[WS_LOGDET + b];
    if ((lane & 15) == 0) {
        const int i = lane >> 4;
        const float mdv = (i & 2) ? ((i & 1) ? md[3] : md[2]) : ((i & 1) ? md[1] : md[0]);
        const float aav = (i & 2) ? ((i & 1) ? aa[3] : aa[2]) : ((i & 1) ? aa[1] : aa[0]);
        const float lsig = fminf(aav, 0.f) - log1pf(expf(-fabsf(aav)));
        out[(size_t)b * NN + n0 + i] = -0.5f * (mdv - corr + ld) + lsig;
    }
}

extern "C" void kernel_launch(void* const* d_in, const int* in_sizes, int n_in,
                              void* d_out, int out_size, void* d_ws, size_t ws_size,
                              hipStream_t stream)
{
    const float* qe   = (const float*)d_in[0];
    const float* ctx  = (const float*)d_in[1];
    const float* W1   = (const float*)d_in[2];
    const float* b1   = (const float*)d_in[3];
    const float* Wd   = (const float*)d_in[4];
    const float* bd   = (const float*)d_in[5];
    const float* WL   = (const float*)d_in[6];
    const float* bL   = (const float*)d_in[7];
    const float* Wdel = (const float*)d_in[8];
    const float* bdel = (const float*)d_in[9];
    const float* Wa   = (const float*)d_in[10];
    const float* ba   = (const float*)d_in[11];
    float* out = (float*)d_out;
    float* ws  = (float*)d_ws;

    ka1_h<<<32, 256, 0, stream>>>(qe, W1, ws);
    ka2_heads<<<304, 256, 0, stream>>>(qe, b1, Wd, bd, WL, bL, Wdel, bdel, Wa, ba, ws);
    kg_gt<<<512, 256, 0, stream>>>(ws);
    kM<<<128, 256, 0, stream>>>(ws);
    kGJ<<<8, 256, 0, stream>>>(ws);
    kc_main<<<1024, 512, 0, stream>>>(ctx, ws, out);
}

// Round 6
// 285.761 us; speedup vs baseline: 1.9010x; 1.1415x over previous
//
#include <hip/hip_runtime.h>
#include <math.h>

#define BB 8
#define NN 4096
#define DD 1024
#define HH 256
#define RR 16

// workspace float offsets
#define WS_GT      0                   // B*R*D = 131072   (G_t[b][r][d])
#define WS_MU      131072              // B*D   = 8192
#define WS_DINV    139264              // B*D
#define WS_ALPHA   147456              // B*D
#define WS_HP      155648              // B*16*H = 32768 (partial h)
#define WS_LDP     188416              // 16*8 = 128
#define WS_MINV    188544              // B*256 = 2048
#define WS_LOGDET  190592              // 16
#define WS_L       190608              // B*D*R = 131072 (ends 321680 floats ~1.3MB)

// ---------------- kernel A1: partial h (split-D 16-way) ----------------
__global__ __launch_bounds__(256) void ka1_h(
    const float* __restrict__ qe, const float* __restrict__ W1, float* __restrict__ ws)
{
    const int b = blockIdx.x >> 4;          // batch
    const int sl = blockIdx.x & 15;         // D-slice of 64
    const int c = threadIdx.x;              // H column
    __shared__ float qe_s[64];
    if (c < 64) qe_s[c] = qe[b * DD + sl * 64 + c];
    __syncthreads();
    float a0 = 0.f, a1 = 0.f, a2 = 0.f, a3 = 0.f;
    const float* W1p = W1 + (sl * 64) * HH;
    #pragma unroll 4
    for (int dl = 0; dl < 64; dl += 4) {
        a0 = fmaf(qe_s[dl + 0], W1p[(dl + 0) * HH + c], a0);
        a1 = fmaf(qe_s[dl + 1], W1p[(dl + 1) * HH + c], a1);
        a2 = fmaf(qe_s[dl + 2], W1p[(dl + 2) * HH + c], a2);
        a3 = fmaf(qe_s[dl + 3], W1p[(dl + 3) * HH + c], a3);
    }
    ws[WS_HP + (b * 16 + sl) * HH + c] = (a0 + a1) + (a2 + a3);
}

// ---------------- kernel A2: all heads; 64 cols/block, 4-way split-H ----------------
// blk 0..15: Wd | 16..31: Wdel | 32..47: Wa | 48..303: WL
__global__ __launch_bounds__(256) void ka2_heads(
    const float* __restrict__ qe, const float* __restrict__ b1,
    const float* __restrict__ Wd, const float* __restrict__ bd,
    const float* __restrict__ WL, const float* __restrict__ bL,
    const float* __restrict__ Wdel, const float* __restrict__ bdel,
    const float* __restrict__ Wa, const float* __restrict__ ba,
    float* __restrict__ ws)
{
    __shared__ float h_s[BB * HH];    // 8 KB
    __shared__ float red[4][512];     // 8 KB
    const int tid = threadIdx.x;

    // finalize h from 16 partials (bias + relu)
    for (int i = tid; i < BB * HH; i += 256) {
        const int bb = i >> 8, c = i & 255;
        float v = b1[c];
        #pragma unroll
        for (int k = 0; k < 16; ++k) v += ws[WS_HP + (bb * 16 + k) * HH + c];
        h_s[i] = fmaxf(v, 0.f);
    }
    __syncthreads();

    const int blk = blockIdx.x;
    const int lane = tid & 63;
    const int u = tid >> 6;

    int mode; const float* W; const float* bias; int base;
    if (blk < 16)       { mode = 0; W = Wd;   bias = bd;   base = 0;  }
    else if (blk < 32)  { mode = 1; W = Wdel; bias = bdel; base = 16; }
    else if (blk < 48)  { mode = 2; W = Wa;   bias = ba;   base = 32; }
    else                { mode = 3; W = WL;   bias = bL;   base = 48; }
    const int ld = (mode == 3) ? (DD * RR) : DD;
    const int cc = (blk - base) * 64 + lane;

    float acc[8];
    #pragma unroll
    for (int b = 0; b < 8; ++b) acc[b] = 0.f;

    #pragma unroll 4
    for (int rr = 0; rr < 64; ++rr) {
        const int r = u * 64 + rr;
        const float wv = W[r * ld + cc];
        #pragma unroll
        for (int b = 0; b < 8; ++b) acc[b] = fmaf(h_s[b * HH + r], wv, acc[b]);
    }
    #pragma unroll
    for (int b = 0; b < 8; ++b) red[u][lane * 8 + b] = acc[b];
    __syncthreads();

    for (int e = tid; e < 512; e += 256) {
        const int cl = e >> 3, bb = e & 7;
        const int cm = (blk - base) * 64 + cl;
        float s = red[0][e] + red[1][e] + red[2][e] + red[3][e] + bias[cm];
        if (mode == 0) {
            const float ldv = fminf(fmaxf(s, -3.f), 3.f);
            ws[WS_DINV + bb * DD + cm] = expf(-ldv);
            red[0][e] = ldv;
        } else if (mode == 1) {
            ws[WS_MU + bb * DD + cm] = qe[bb * DD + cm] + 0.1f * s;
        } else if (mode == 2) {
            ws[WS_ALPHA + bb * DD + cm] = s;
        } else {
            ws[WS_L + bb * (DD * RR) + cm] = 0.1f * s;
        }
    }
    if (mode == 0) {
        __syncthreads();
        if (tid < 8) {
            float s = 0.f;
            for (int cl = 0; cl < 64; ++cl) s += red[0][cl * 8 + tid];
            ws[WS_LDP + blk * 8 + tid] = s;
        }
    }
}

// ---------------- kernel G: G_t[b][r][d] = dinv[b][d] * L[b][d][r] ----------------
__global__ __launch_bounds__(256) void kg_gt(float* __restrict__ ws)
{
    const int idx = blockIdx.x * 256 + threadIdx.x;   // 512 blocks -> B*R*D
    const int d = idx & (DD - 1);
    const int r = (idx >> 10) & (RR - 1);
    const int b = idx >> 14;
    ws[WS_GT + idx] = ws[WS_DINV + b * DD + d] * ws[WS_L + (b * DD + d) * RR + r];
}

// ---------------- kernel MGJ: M = I + Gt L, invert (GJ), logdet ----------------
__global__ __launch_bounds__(1024) void kMGJ(float* __restrict__ ws)
{
    const int b = blockIdx.x;
    const int tid = threadIdx.x;
    const int dgr = tid >> 8;            // 0..3 d-slice
    const int gs = tid & 255;
    const int g = gs >> 4, s = gs & 15;

    const float* Gt = ws + WS_GT + (size_t)b * (RR * DD);
    const float* Lp = ws + WS_L + (size_t)b * (DD * RR);

    float acc = 0.f;
    #pragma unroll 8
    for (int k = 0; k < 256; ++k) {
        const int d = dgr * 256 + k;
        acc = fmaf(Gt[g * DD + d], Lp[d * 16 + s], acc);
    }

    __shared__ float Mp[4][256];
    __shared__ float A[16][33];
    Mp[dgr][gs] = acc;
    __syncthreads();

    const bool act = (tid < 256);
    if (act) {
        A[g][s] = ((g == s) ? 1.f : 0.f) + Mp[0][gs] + Mp[1][gs] + Mp[2][gs] + Mp[3][gs];
        A[g][s + 16] = (g == s) ? 1.f : 0.f;
    }
    __syncthreads();

    float logdetM = 0.f;
    for (int k = 0; k < 16; ++k) {
        const float piv = A[k][k];
        if (tid == 0) logdetM += logf(piv);
        __syncthreads();
        if (act && g == k) {
            const float rinv = 1.f / piv;
            A[g][s] *= rinv;
            A[g][s + 16] *= rinv;
        }
        __syncthreads();
        const float f = (act && g != k) ? A[g][k] : 0.f;
        __syncthreads();
        if (act && g != k) {
            A[g][s]      = fmaf(-f, A[k][s],      A[g][s]);
            A[g][s + 16] = fmaf(-f, A[k][s + 16], A[g][s + 16]);
        }
        __syncthreads();
    }
    if (act) ws[WS_MINV + b * 256 + g * 16 + s] = A[g][s + 16];
    if (tid == 0) {
        float lds = 0.f;
        for (int k = 0; k < 16; ++k) lds += ws[WS_LDP + k * 8 + b];
        ws[WS_LOGDET + b] = lds + logdetM;
    }
}

// ---------------- kernel C: main streaming pass (Gt in LDS) ----------------
__global__ __launch_bounds__(512, 2) void kc_main(
    const float* __restrict__ ctx, const float* __restrict__ ws, float* __restrict__ out)
{
    const int bid = blockIdx.x;          // 1024 blocks
    const int b = bid >> 7;              // 128 tiles of 32 rows per batch
    const int tile = bid & 127;
    const int wave = threadIdx.x >> 6;   // 0..7
    const int lane = threadIdx.x & 63;
    const int n0 = tile * 32 + wave * 4;

    __shared__ float gt_s[RR * DD];      // 64 KB, r-major (conflict-free 16B-stride reads)
    {
        float4* gs4 = (float4*)gt_s;
        const float4* Gt4g = (const float4*)(ws + WS_GT + (size_t)b * (RR * DD));
        for (int i = threadIdx.x; i < RR * DD / 4; i += 512) gs4[i] = Gt4g[i];
    }
    __syncthreads();
    const float4* gs4 = (const float4*)gt_s;

    const float4* mu4 = (const float4*)(ws + WS_MU + b * DD);
    const float4* dv4 = (const float4*)(ws + WS_DINV + b * DD);
    const float4* al4 = (const float4*)(ws + WS_ALPHA + b * DD);
    const float4* ctx4 = (const float4*)(ctx + ((size_t)(b * NN + n0)) * DD);

    float g[4][16];
    float md[4], aa[4];
    #pragma unroll
    for (int i = 0; i < 4; ++i) {
        md[i] = 0.f; aa[i] = 0.f;
        #pragma unroll
        for (int r = 0; r < 16; ++r) g[i][r] = 0.f;
    }

    #pragma unroll 2
    for (int step = 0; step < 4; ++step) {
        const int fi = step * 64 + lane;      // float4 index within D
        const float4 c0 = ctx4[0 * (DD / 4) + fi];
        const float4 c1 = ctx4[1 * (DD / 4) + fi];
        const float4 c2 = ctx4[2 * (DD / 4) + fi];
        const float4 c3 = ctx4[3 * (DD / 4) + fi];
        const float4 mv = mu4[fi];

        float diff[4][4];
        diff[0][0] = c0.x - mv.x; diff[0][1] = c0.y - mv.y; diff[0][2] = c0.z - mv.z; diff[0][3] = c0.w - mv.w;
        diff[1][0] = c1.x - mv.x; diff[1][1] = c1.y - mv.y; diff[1][2] = c1.z - mv.z; diff[1][3] = c1.w - mv.w;
        diff[2][0] = c2.x - mv.x; diff[2][1] = c2.y - mv.y; diff[2][2] = c2.z - mv.z; diff[2][3] = c2.w - mv.w;
        diff[3][0] = c3.x - mv.x; diff[3][1] = c3.y - mv.y; diff[3][2] = c3.z - mv.z; diff[3][3] = c3.w - mv.w;

        {   // md/aa first, then dvv/av registers die
            const float4 dvv = dv4[fi];
            const float4 av = al4[fi];
            const float dva[4] = {dvv.x, dvv.y, dvv.z, dvv.w};
            const float ava[4] = {av.x, av.y, av.z, av.w};
            #pragma unroll
            for (int i = 0; i < 4; ++i) {
                #pragma unroll
                for (int j = 0; j < 4; ++j) {
                    md[i] = fmaf(diff[i][j] * dva[j], diff[i][j], md[i]);
                    aa[i] = fmaf(ava[j], diff[i][j], aa[i]);
                }
            }
        }

        #pragma unroll
        for (int r = 0; r < 16; ++r) {
            const float4 gt = gs4[r * 256 + fi];
            #pragma unroll
            for (int i = 0; i < 4; ++i) {
                g[i][r] = fmaf(gt.x, diff[i][0], g[i][r]);
                g[i][r] = fmaf(gt.y, diff[i][1], g[i][r]);
                g[i][r] = fmaf(gt.z, diff[i][2], g[i][r]);
                g[i][r] = fmaf(gt.w, diff[i][3], g[i][r]);
            }
        }
    }

    // fold-halving transpose-reduce: 64 slots (row i, r) across 64 lanes.
    float v[64];
    #pragma unroll
    for (int i = 0; i < 4; ++i)
        #pragma unroll
        for (int r = 0; r < 16; ++r) v[i * 16 + r] = g[i][r];

    #pragma unroll
    for (int s6 = 0; s6 < 6; ++s6) {
        const int m = 1 << s6;
        const int half = 32 >> s6;
        const bool up = (lane & m) != 0;
        #pragma unroll
        for (int ii = 0; ii < half; ++ii) {
            float x0 = v[2 * ii], x1 = v[2 * ii + 1];
            float y0 = __shfl_xor(x0, m, 64);
            float y1 = __shfl_xor(x1, m, 64);
            v[ii] = up ? (x1 + y1) : (x0 + y0);
        }
    }
    const float w = v[0];

    #pragma unroll
    for (int m = 1; m < 64; m <<= 1) {
        #pragma unroll
        for (int i = 0; i < 4; ++i) {
            md[i] += __shfl_xor(md[i], m, 64);
            aa[i] += __shfl_xor(aa[i], m, 64);
        }
    }

    const int r = lane & 15;
    const int rowbase = lane & 48;
    const float* Minv = ws + WS_MINV + b * 256 + r * 16;
    float y = 0.f;
    #pragma unroll
    for (int s = 0; s < 16; ++s) y = fmaf(Minv[s], __shfl(w, rowbase + s, 64), y);
    float corr = w * y;
    corr += __shfl_xor(corr, 1, 64);
    corr += __shfl_xor(corr, 2, 64);
    corr += __shfl_xor(corr, 4, 64);
    corr += __shfl_xor(corr, 8, 64);

    const float ld = ws[WS_LOGDET + b];
    if ((lane & 15) == 0) {
        const int i = lane >> 4;
        const float mdv = (i & 2) ? ((i & 1) ? md[3] : md[2]) : ((i & 1) ? md[1] : md[0]);
        const float aav = (i & 2) ? ((i & 1) ? aa[3] : aa[2]) : ((i & 1) ? aa[1] : aa[0]);
        const float lsig = fminf(aav, 0.f) - log1pf(expf(-fabsf(aav)));
        out[(size_t)b * NN + n0 + i] = -0.5f * (mdv - corr + ld) + lsig;
    }
}

extern "C" void kernel_launch(void* const* d_in, const int* in_sizes, int n_in,
                              void* d_out, int out_size, void* d_ws, size_t ws_size,
                              hipStream_t stream)
{
    const float* qe   = (const float*)d_in[0];
    const float* ctx  = (const float*)d_in[1];
    const float* W1   = (const float*)d_in[2];
    const float* b1   = (const float*)d_in[3];
    const float* Wd   = (const float*)d_in[4];
    const float* bd   = (const float*)d_in[5];
    const float* WL   = (const float*)d_in[6];
    const float* bL   = (const float*)d_in[7];
    const float* Wdel = (const float*)d_in[8];
    const float* bdel = (const float*)d_in[9];
    const float* Wa   = (const float*)d_in[10];
    const float* ba   = (const float*)d_in[11];
    float* out = (float*)d_out;
    float* ws  = (float*)d_ws;

    ka1_h<<<128, 256, 0, stream>>>(qe, W1, ws);
    ka2_heads<<<304, 256, 0, stream>>>(qe, b1, Wd, bd, WL, bL, Wdel, bdel, Wa, ba, ws);
    kg_gt<<<512, 256, 0, stream>>>(ws);
    kMGJ<<<8, 1024, 0, stream>>>(ws);
    kc_main<<<1024, 512, 0, stream>>>(ctx, ws, out);
}

// Round 7
// 282.646 us; speedup vs baseline: 1.9220x; 1.0110x over previous
//
#include <hip/hip_runtime.h>
#include <math.h>

#define BB 8
#define NN 4096
#define DD 1024
#define HH 256
#define RR 16

// workspace float offsets
#define WS_GT      0                   // B*R*D = 131072   (G_t[b][r][d])
#define WS_MU      131072              // B*D   = 8192
#define WS_DINV    139264              // B*D
#define WS_ALPHA   147456              // B*D
#define WS_HP      155648              // B*16*H = 32768 (partial h)
#define WS_LDP     188416              // 16*8 = 128
#define WS_MINV    188544              // B*256 = 2048
#define WS_LOGDET  190592              // 16
#define WS_L       190608              // B*D*R = 131072 (ends 321680 floats ~1.3MB)

typedef __attribute__((address_space(3))) unsigned int lds_uint;
typedef __attribute__((address_space(1))) const unsigned int g_uint;

// ---------------- kernel A1: partial h (split-D 16-way) ----------------
__global__ __launch_bounds__(256) void ka1_h(
    const float* __restrict__ qe, const float* __restrict__ W1, float* __restrict__ ws)
{
    const int b = blockIdx.x >> 4;
    const int sl = blockIdx.x & 15;
    const int c = threadIdx.x;
    __shared__ float qe_s[64];
    if (c < 64) qe_s[c] = qe[b * DD + sl * 64 + c];
    __syncthreads();
    float a0 = 0.f, a1 = 0.f, a2 = 0.f, a3 = 0.f;
    const float* W1p = W1 + (sl * 64) * HH;
    #pragma unroll 4
    for (int dl = 0; dl < 64; dl += 4) {
        a0 = fmaf(qe_s[dl + 0], W1p[(dl + 0) * HH + c], a0);
        a1 = fmaf(qe_s[dl + 1], W1p[(dl + 1) * HH + c], a1);
        a2 = fmaf(qe_s[dl + 2], W1p[(dl + 2) * HH + c], a2);
        a3 = fmaf(qe_s[dl + 3], W1p[(dl + 3) * HH + c], a3);
    }
    ws[WS_HP + (b * 16 + sl) * HH + c] = (a0 + a1) + (a2 + a3);
}

// ---------------- kernel A2: all heads; 64 cols/block, 4-way split-H ----------------
__global__ __launch_bounds__(256) void ka2_heads(
    const float* __restrict__ qe, const float* __restrict__ b1,
    const float* __restrict__ Wd, const float* __restrict__ bd,
    const float* __restrict__ WL, const float* __restrict__ bL,
    const float* __restrict__ Wdel, const float* __restrict__ bdel,
    const float* __restrict__ Wa, const float* __restrict__ ba,
    float* __restrict__ ws)
{
    __shared__ float h_s[BB * HH];
    __shared__ float red[4][512];
    const int tid = threadIdx.x;

    for (int i = tid; i < BB * HH; i += 256) {
        const int bb = i >> 8, c = i & 255;
        float v = b1[c];
        #pragma unroll
        for (int k = 0; k < 16; ++k) v += ws[WS_HP + (bb * 16 + k) * HH + c];
        h_s[i] = fmaxf(v, 0.f);
    }
    __syncthreads();

    const int blk = blockIdx.x;
    const int lane = tid & 63;
    const int u = tid >> 6;

    int mode; const float* W; const float* bias; int base;
    if (blk < 16)       { mode = 0; W = Wd;   bias = bd;   base = 0;  }
    else if (blk < 32)  { mode = 1; W = Wdel; bias = bdel; base = 16; }
    else if (blk < 48)  { mode = 2; W = Wa;   bias = ba;   base = 32; }
    else                { mode = 3; W = WL;   bias = bL;   base = 48; }
    const int ld = (mode == 3) ? (DD * RR) : DD;
    const int cc = (blk - base) * 64 + lane;

    float acc[8];
    #pragma unroll
    for (int b = 0; b < 8; ++b) acc[b] = 0.f;

    #pragma unroll 4
    for (int rr = 0; rr < 64; ++rr) {
        const int r = u * 64 + rr;
        const float wv = W[r * ld + cc];
        #pragma unroll
        for (int b = 0; b < 8; ++b) acc[b] = fmaf(h_s[b * HH + r], wv, acc[b]);
    }
    #pragma unroll
    for (int b = 0; b < 8; ++b) red[u][lane * 8 + b] = acc[b];
    __syncthreads();

    for (int e = tid; e < 512; e += 256) {
        const int cl = e >> 3, bb = e & 7;
        const int cm = (blk - base) * 64 + cl;
        float s = red[0][e] + red[1][e] + red[2][e] + red[3][e] + bias[cm];
        if (mode == 0) {
            const float ldv = fminf(fmaxf(s, -3.f), 3.f);
            ws[WS_DINV + bb * DD + cm] = expf(-ldv);
            red[0][e] = ldv;
        } else if (mode == 1) {
            ws[WS_MU + bb * DD + cm] = qe[bb * DD + cm] + 0.1f * s;
        } else if (mode == 2) {
            ws[WS_ALPHA + bb * DD + cm] = s;
        } else {
            ws[WS_L + bb * (DD * RR) + cm] = 0.1f * s;
        }
    }
    if (mode == 0) {
        __syncthreads();
        if (tid < 8) {
            float s = 0.f;
            for (int cl = 0; cl < 64; ++cl) s += red[0][cl * 8 + tid];
            ws[WS_LDP + blk * 8 + tid] = s;
        }
    }
}

// ---------------- kernel G: G_t[b][r][d] = dinv[b][d] * L[b][d][r] ----------------
__global__ __launch_bounds__(256) void kg_gt(float* __restrict__ ws)
{
    const int idx = blockIdx.x * 256 + threadIdx.x;
    const int d = idx & (DD - 1);
    const int r = (idx >> 10) & (RR - 1);
    const int b = idx >> 14;
    ws[WS_GT + idx] = ws[WS_DINV + b * DD + d] * ws[WS_L + (b * DD + d) * RR + r];
}

// ---------------- kernel MGJ: M = I + Gt L, invert (GJ), logdet ----------------
__global__ __launch_bounds__(1024) void kMGJ(float* __restrict__ ws)
{
    const int b = blockIdx.x;
    const int tid = threadIdx.x;
    const int dgr = tid >> 8;
    const int gs = tid & 255;
    const int g = gs >> 4, s = gs & 15;

    const float* Gt = ws + WS_GT + (size_t)b * (RR * DD);
    const float* Lp = ws + WS_L + (size_t)b * (DD * RR);

    float acc = 0.f;
    #pragma unroll 8
    for (int k = 0; k < 256; ++k) {
        const int d = dgr * 256 + k;
        acc = fmaf(Gt[g * DD + d], Lp[d * 16 + s], acc);
    }

    __shared__ float Mp[4][256];
    __shared__ float A[16][33];
    Mp[dgr][gs] = acc;
    __syncthreads();

    const bool act = (tid < 256);
    if (act) {
        A[g][s] = ((g == s) ? 1.f : 0.f) + Mp[0][gs] + Mp[1][gs] + Mp[2][gs] + Mp[3][gs];
        A[g][s + 16] = (g == s) ? 1.f : 0.f;
    }
    __syncthreads();

    float logdetM = 0.f;
    for (int k = 0; k < 16; ++k) {
        const float piv = A[k][k];
        if (tid == 0) logdetM += logf(piv);
        __syncthreads();
        if (act && g == k) {
            const float rinv = 1.f / piv;
            A[g][s] *= rinv;
            A[g][s + 16] *= rinv;
        }
        __syncthreads();
        const float f = (act && g != k) ? A[g][k] : 0.f;
        __syncthreads();
        if (act && g != k) {
            A[g][s]      = fmaf(-f, A[k][s],      A[g][s]);
            A[g][s + 16] = fmaf(-f, A[k][s + 16], A[g][s + 16]);
        }
        __syncthreads();
    }
    if (act) ws[WS_MINV + b * 256 + g * 16 + s] = A[g][s + 16];
    if (tid == 0) {
        float lds = 0.f;
        for (int k = 0; k < 16; ++k) lds += ws[WS_LDP + k * 8 + b];
        ws[WS_LOGDET + b] = lds + logdetM;
    }
}

// ---------------- kernel C: DMA-staged streaming pass ----------------
// block: 512 thr (8 waves), 32 rows; lane = 16 per row; 16 chunks of 64 d
__global__ __launch_bounds__(512, 2) void kc_main(
    const float* __restrict__ ctx, const float* __restrict__ ws, float* __restrict__ out)
{
    const int bid = blockIdx.x;          // 1024 blocks
    const int b = bid >> 7;
    const int tile = bid & 127;
    const int tid = threadIdx.x;
    const int wave = tid >> 6;
    const int lane = tid & 63;
    const int n0 = tile * 32;

    __shared__ float gt_s[RR * DD];      // 64 KB [r][d]
    __shared__ float cbuf[2][32 * 64];   // 2 x 8 KB, f4-swizzled rows

    // ---- prologue: DMA Gt (8 slots/thread) + ctx chunk 0 (1 slot/thread)
    {
        const float* gtg = ws + WS_GT + (size_t)b * (RR * DD);
        #pragma unroll
        for (int k = 0; k < 8; ++k) {
            // slot = k*512 + wave*64 + lane ; dest uniform part = (k*512 + wave*64)*16B
            __builtin_amdgcn_global_load_lds(
                (g_uint*)(gtg + (size_t)(k * 512 + wave * 64 + lane) * 4),
                (lds_uint*)((unsigned int*)gt_s + (k * 512 + wave * 64) * 4),
                16, 0, 0);
        }
        // ctx chunk 0: slot i = tid: row = i>>4, f4dst = i&15, f4src = f4dst ^ (row&7)
        const int row = tid >> 4, f4 = tid & 15;
        const float* src = ctx + ((size_t)(b * NN + n0 + row)) * DD + (0 * 64) + ((f4 ^ (row & 7)) * 4);
        __builtin_amdgcn_global_load_lds(
            (g_uint*)src,
            (lds_uint*)((unsigned int*)&cbuf[0][0] + (wave * 64) * 4),
            16, 0, 0);
    }
    asm volatile("s_waitcnt vmcnt(0)" ::: "memory");
    __syncthreads();

    const int rl = lane >> 4;            // row within wave quad (0..3)
    const int row_blk = wave * 4 + rl;   // row within 32-row tile
    const int f4 = lane & 15;
    const float4* gt4 = (const float4*)gt_s;
    const float4* mu4 = (const float4*)(ws + WS_MU + b * DD);
    const float4* dv4 = (const float4*)(ws + WS_DINV + b * DD);
    const float4* al4 = (const float4*)(ws + WS_ALPHA + b * DD);

    float g[16];
    #pragma unroll
    for (int r = 0; r < 16; ++r) g[r] = 0.f;
    float md = 0.f, aa = 0.f;

    const int stage_row = tid >> 4, stage_f4 = tid & 15;
    const float* stage_base = ctx + ((size_t)(b * NN + n0 + stage_row)) * DD + ((stage_f4 ^ (stage_row & 7)) * 4);

    for (int t = 0; t < 16; ++t) {
        if (t + 1 < 16) {
            __builtin_amdgcn_global_load_lds(
                (g_uint*)(stage_base + (t + 1) * 64),
                (lds_uint*)((unsigned int*)&cbuf[(t + 1) & 1][0] + (wave * 64) * 4),
                16, 0, 0);
            asm volatile("s_waitcnt vmcnt(1)" ::: "memory");
        } else {
            asm volatile("s_waitcnt vmcnt(0)" ::: "memory");
        }
        __syncthreads();

        // compute chunk t: this lane's 4 d at fi = t*16 + f4
        const int fi = t * 16 + f4;
        const float4* cb4 = (const float4*)&cbuf[t & 1][0];
        const float4 cv = cb4[row_blk * 16 + (f4 ^ (row_blk & 7))];
        const float4 mv = mu4[fi];
        const float4 dvv = dv4[fi];
        const float4 av = al4[fi];

        const float d0 = cv.x - mv.x, d1 = cv.y - mv.y, d2 = cv.z - mv.z, d3 = cv.w - mv.w;
        md = fmaf(d0 * dvv.x, d0, md); md = fmaf(d1 * dvv.y, d1, md);
        md = fmaf(d2 * dvv.z, d2, md); md = fmaf(d3 * dvv.w, d3, md);
        aa = fmaf(av.x, d0, aa); aa = fmaf(av.y, d1, aa);
        aa = fmaf(av.z, d2, aa); aa = fmaf(av.w, d3, aa);

        #pragma unroll
        for (int r = 0; r < 16; ++r) {
            const float4 gt = gt4[r * 256 + fi];
            g[r] = fmaf(gt.x, d0, g[r]);
            g[r] = fmaf(gt.y, d1, g[r]);
            g[r] = fmaf(gt.z, d2, g[r]);
            g[r] = fmaf(gt.w, d3, g[r]);
        }
        __syncthreads();
    }

    // ---- epilogue: fold g[16] within each 16-lane row-group (4 stages)
    float v[16];
    #pragma unroll
    for (int r = 0; r < 16; ++r) v[r] = g[r];

    #pragma unroll
    for (int s4 = 0; s4 < 4; ++s4) {
        const int m = 1 << s4;
        const int half = 8 >> s4;
        const bool up = (lane & m) != 0;
        #pragma unroll
        for (int ii = 0; ii < half; ++ii) {
            float x0 = v[2 * ii], x1 = v[2 * ii + 1];
            float y0 = __shfl_xor(x0, m, 64);
            float y1 = __shfl_xor(x1, m, 64);
            v[ii] = up ? (x1 + y1) : (x0 + y0);
        }
    }
    const float w = v[0];                // w[r = lane&15] for row row_blk

    // md/aa reduce within 16-lane group
    #pragma unroll
    for (int m = 1; m < 16; m <<= 1) {
        md += __shfl_xor(md, m, 64);
        aa += __shfl_xor(aa, m, 64);
    }

    // corr = w^T Minv w
    const int r = lane & 15;
    const int base16 = lane & 48;
    const float* Minv = ws + WS_MINV + b * 256 + r * 16;
    float y = 0.f;
    #pragma unroll
    for (int s = 0; s < 16; ++s) y = fmaf(Minv[s], __shfl(w, base16 + s, 64), y);
    float corr = w * y;
    corr += __shfl_xor(corr, 1, 64);
    corr += __shfl_xor(corr, 2, 64);
    corr += __shfl_xor(corr, 4, 64);
    corr += __shfl_xor(corr, 8, 64);

    if (f4 == 0) {
        const float ld = ws[WS_LOGDET + b];
        const float lsig = fminf(aa, 0.f) - log1pf(expf(-fabsf(aa)));
        out[(size_t)b * NN + n0 + row_blk] = -0.5f * (md - corr + ld) + lsig;
    }
}

extern "C" void kernel_launch(void* const* d_in, const int* in_sizes, int n_in,
                              void* d_out, int out_size, void* d_ws, size_t ws_size,
                              hipStream_t stream)
{
    const float* qe   = (const float*)d_in[0];
    const float* ctx  = (const float*)d_in[1];
    const float* W1   = (const float*)d_in[2];
    const float* b1   = (const float*)d_in[3];
    const float* Wd   = (const float*)d_in[4];
    const float* bd   = (const float*)d_in[5];
    const float* WL   = (const float*)d_in[6];
    const float* bL   = (const float*)d_in[7];
    const float* Wdel = (const float*)d_in[8];
    const float* bdel = (const float*)d_in[9];
    const float* Wa   = (const float*)d_in[10];
    const float* ba   = (const float*)d_in[11];
    float* out = (float*)d_out;
    float* ws  = (float*)d_ws;

    ka1_h<<<128, 256, 0, stream>>>(qe, W1, ws);
    ka2_heads<<<304, 256, 0, stream>>>(qe, b1, Wd, bd, WL, bL, Wdel, bdel, Wa, ba, ws);
    kg_gt<<<512, 256, 0, stream>>>(ws);
    kMGJ<<<8, 1024, 0, stream>>>(ws);
    kc_main<<<1024, 512, 0, stream>>>(ctx, ws, out);
}

// Round 8
// 282.218 us; speedup vs baseline: 1.9249x; 1.0015x over previous
//
#include <hip/hip_runtime.h>
#include <math.h>

#define BB 8
#define NN 4096
#define DD 1024
#define HH 256
#define RR 16

// workspace float offsets
#define WS_GT      0                   // B*R*D = 131072   (G_t[b][r][d])
#define WS_MU      131072              // B*D   = 8192
#define WS_DINV    139264              // B*D   (== WS_MU + 8192)
#define WS_ALPHA   147456              // B*D   (== WS_MU + 16384)
#define WS_HP      155648              // B*16*H = 32768 (partial h)
#define WS_LDP     188416              // 16*8 = 128
#define WS_MINV    188544              // B*256 = 2048
#define WS_LOGDET  190592              // 16
#define WS_L       190608              // B*D*R = 131072 (ends 321680 floats ~1.3MB)

typedef __attribute__((address_space(3))) unsigned int lds_uint;
typedef __attribute__((address_space(1))) const unsigned int g_uint;

// ---------------- kernel A1: partial h (split-D 16-way) ----------------
__global__ __launch_bounds__(256) void ka1_h(
    const float* __restrict__ qe, const float* __restrict__ W1, float* __restrict__ ws)
{
    const int b = blockIdx.x >> 4;
    const int sl = blockIdx.x & 15;
    const int c = threadIdx.x;
    __shared__ float qe_s[64];
    if (c < 64) qe_s[c] = qe[b * DD + sl * 64 + c];
    __syncthreads();
    float a0 = 0.f, a1 = 0.f, a2 = 0.f, a3 = 0.f;
    const float* W1p = W1 + (sl * 64) * HH;
    #pragma unroll 4
    for (int dl = 0; dl < 64; dl += 4) {
        a0 = fmaf(qe_s[dl + 0], W1p[(dl + 0) * HH + c], a0);
        a1 = fmaf(qe_s[dl + 1], W1p[(dl + 1) * HH + c], a1);
        a2 = fmaf(qe_s[dl + 2], W1p[(dl + 2) * HH + c], a2);
        a3 = fmaf(qe_s[dl + 3], W1p[(dl + 3) * HH + c], a3);
    }
    ws[WS_HP + (b * 16 + sl) * HH + c] = (a0 + a1) + (a2 + a3);
}

// ---------------- kernel A2: all heads; 64 cols/block, 4-way split-H ----------------
__global__ __launch_bounds__(256) void ka2_heads(
    const float* __restrict__ qe, const float* __restrict__ b1,
    const float* __restrict__ Wd, const float* __restrict__ bd,
    const float* __restrict__ WL, const float* __restrict__ bL,
    const float* __restrict__ Wdel, const float* __restrict__ bdel,
    const float* __restrict__ Wa, const float* __restrict__ ba,
    float* __restrict__ ws)
{
    __shared__ float h_s[BB * HH];
    __shared__ float red[4][512];
    const int tid = threadIdx.x;

    for (int i = tid; i < BB * HH; i += 256) {
        const int bb = i >> 8, c = i & 255;
        float v = b1[c];
        #pragma unroll
        for (int k = 0; k < 16; ++k) v += ws[WS_HP + (bb * 16 + k) * HH + c];
        h_s[i] = fmaxf(v, 0.f);
    }
    __syncthreads();

    const int blk = blockIdx.x;
    const int lane = tid & 63;
    const int u = tid >> 6;

    int mode; const float* W; const float* bias; int base;
    if (blk < 16)       { mode = 0; W = Wd;   bias = bd;   base = 0;  }
    else if (blk < 32)  { mode = 1; W = Wdel; bias = bdel; base = 16; }
    else if (blk < 48)  { mode = 2; W = Wa;   bias = ba;   base = 32; }
    else                { mode = 3; W = WL;   bias = bL;   base = 48; }
    const int ld = (mode == 3) ? (DD * RR) : DD;
    const int cc = (blk - base) * 64 + lane;

    float acc[8];
    #pragma unroll
    for (int b = 0; b < 8; ++b) acc[b] = 0.f;

    #pragma unroll 4
    for (int rr = 0; rr < 64; ++rr) {
        const int r = u * 64 + rr;
        const float wv = W[r * ld + cc];
        #pragma unroll
        for (int b = 0; b < 8; ++b) acc[b] = fmaf(h_s[b * HH + r], wv, acc[b]);
    }
    #pragma unroll
    for (int b = 0; b < 8; ++b) red[u][lane * 8 + b] = acc[b];
    __syncthreads();

    for (int e = tid; e < 512; e += 256) {
        const int cl = e >> 3, bb = e & 7;
        const int cm = (blk - base) * 64 + cl;
        float s = red[0][e] + red[1][e] + red[2][e] + red[3][e] + bias[cm];
        if (mode == 0) {
            const float ldv = fminf(fmaxf(s, -3.f), 3.f);
            ws[WS_DINV + bb * DD + cm] = expf(-ldv);
            red[0][e] = ldv;
        } else if (mode == 1) {
            ws[WS_MU + bb * DD + cm] = qe[bb * DD + cm] + 0.1f * s;
        } else if (mode == 2) {
            ws[WS_ALPHA + bb * DD + cm] = s;
        } else {
            ws[WS_L + bb * (DD * RR) + cm] = 0.1f * s;
        }
    }
    if (mode == 0) {
        __syncthreads();
        if (tid < 8) {
            float s = 0.f;
            for (int cl = 0; cl < 64; ++cl) s += red[0][cl * 8 + tid];
            ws[WS_LDP + blk * 8 + tid] = s;
        }
    }
}

// ---------------- kernel G: G_t[b][r][d] = dinv[b][d] * L[b][d][r] ----------------
__global__ __launch_bounds__(256) void kg_gt(float* __restrict__ ws)
{
    const int idx = blockIdx.x * 256 + threadIdx.x;
    const int d = idx & (DD - 1);
    const int r = (idx >> 10) & (RR - 1);
    const int b = idx >> 14;
    ws[WS_GT + idx] = ws[WS_DINV + b * DD + d] * ws[WS_L + (b * DD + d) * RR + r];
}

// ---------------- kernel MGJ: M = I + Gt L, invert (GJ), logdet ----------------
__global__ __launch_bounds__(1024) void kMGJ(float* __restrict__ ws)
{
    const int b = blockIdx.x;
    const int tid = threadIdx.x;
    const int dgr = tid >> 8;
    const int gs = tid & 255;
    const int g = gs >> 4, s = gs & 15;

    const float* Gt = ws + WS_GT + (size_t)b * (RR * DD);
    const float* Lp = ws + WS_L + (size_t)b * (DD * RR);

    float acc = 0.f;
    #pragma unroll 8
    for (int k = 0; k < 256; ++k) {
        const int d = dgr * 256 + k;
        acc = fmaf(Gt[g * DD + d], Lp[d * 16 + s], acc);
    }

    __shared__ float Mp[4][256];
    __shared__ float A[16][33];
    Mp[dgr][gs] = acc;
    __syncthreads();

    const bool act = (tid < 256);
    if (act) {
        A[g][s] = ((g == s) ? 1.f : 0.f) + Mp[0][gs] + Mp[1][gs] + Mp[2][gs] + Mp[3][gs];
        A[g][s + 16] = (g == s) ? 1.f : 0.f;
    }
    __syncthreads();

    float logdetM = 0.f;
    for (int k = 0; k < 16; ++k) {
        const float piv = A[k][k];
        if (tid == 0) logdetM += logf(piv);
        __syncthreads();
        if (act && g == k) {
            const float rinv = 1.f / piv;
            A[g][s] *= rinv;
            A[g][s + 16] *= rinv;
        }
        __syncthreads();
        const float f = (act && g != k) ? A[g][k] : 0.f;
        __syncthreads();
        if (act && g != k) {
            A[g][s]      = fmaf(-f, A[k][s],      A[g][s]);
            A[g][s + 16] = fmaf(-f, A[k][s + 16], A[g][s + 16]);
        }
        __syncthreads();
    }
    if (act) ws[WS_MINV + b * 256 + g * 16 + s] = A[g][s + 16];
    if (tid == 0) {
        float lds = 0.f;
        for (int k = 0; k < 16; ++k) lds += ws[WS_LDP + k * 8 + b];
        ws[WS_LOGDET + b] = lds + logdetM;
    }
}

// ---------------- kernel C v4: barrier-free wave-private DMA pipeline ----------------
// 256 blocks (1/CU), 512 thr (8 waves), 128 rows/block, 16 rows/wave.
// Lane = (slot 0..3, f4 0..15); lane owns rows slot*4+k (k=0..3), d-columns f4*4..f4*4+3 per chunk.
__global__ __launch_bounds__(512, 1) void kc_main(
    const float* __restrict__ ctx, const float* __restrict__ ws, float* __restrict__ out)
{
    const int bid = blockIdx.x;          // 256 blocks
    const int b = bid >> 5;              // 32 tiles per batch
    const int tile = bid & 31;
    const int tid = threadIdx.x;
    const int wave = tid >> 6;
    const int lane = tid & 63;
    const int slot = lane >> 4;
    const int f4 = lane & 15;
    const int n0 = tile * 128;

    __shared__ float gt_s[RR * DD];        // 64 KB  [r][d]
    __shared__ float prm_s[3 * DD];        // 12 KB  mu | dinv | alpha
    __shared__ float minv_s[256];          // 1 KB   (symmetric)
    __shared__ float cbuf[2][8][16][64];   // 64 KB ring, wave-private [buf][wave][row16][d64]

    // ---- prologue: stage Gt via DMA, params/Minv via registers
    {
        const float* gtg = ws + WS_GT + (size_t)b * (RR * DD);
        #pragma unroll
        for (int k = 0; k < 8; ++k)
            __builtin_amdgcn_global_load_lds(
                (g_uint*)(gtg + (size_t)(k * 512 + wave * 64 + lane) * 4),
                (lds_uint*)((unsigned int*)gt_s + (k * 512 + wave * 64) * 4),
                16, 0, 0);
        #pragma unroll
        for (int i0 = 0; i0 < 2; ++i0) {
            const int i = tid + i0 * 512;
            if (i < 768) {
                const int arr = i >> 8, off = i & 255;
                ((float4*)prm_s)[arr * 256 + off] =
                    *(const float4*)(ws + WS_MU + arr * 8192 + b * DD + off * 4);
            }
        }
        if (tid < 256) minv_s[tid] = ws[WS_MINV + b * 256 + tid];
    }
    __syncthreads();   // drains vmcnt(0) too (Gt DMA complete)

    // per-lane DMA source pointers for its 4 staging rows (one per instr j)
    const float* srcp[4];
    #pragma unroll
    for (int j = 0; j < 4; ++j) {
        const int rl = j * 4 + (lane >> 4);      // row_local this lane stages in instr j
        srcp[j] = ctx + ((size_t)(b * NN + n0 + wave * 16 + rl)) * DD + ((lane & 15) ^ rl) * 4;
    }

    auto ISSUE = [&](int tt) {
        float* dbase = &cbuf[tt & 1][wave][0][0];
        #pragma unroll
        for (int j = 0; j < 4; ++j)
            __builtin_amdgcn_global_load_lds(
                (g_uint*)(srcp[j] + tt * 64),
                (lds_uint*)(dbase + j * 256),
                16, 0, 0);
    };

    ISSUE(0);

    const float4* gt4 = (const float4*)gt_s;
    const float4* prm4 = (const float4*)prm_s;

    float g[4][16];
    float md[4], aa[4];
    #pragma unroll
    for (int k = 0; k < 4; ++k) {
        md[k] = 0.f; aa[k] = 0.f;
        #pragma unroll
        for (int r = 0; r < 16; ++r) g[k][r] = 0.f;
    }

    for (int t = 0; t < 16; ++t) {
        if (t + 1 < 16) ISSUE(t + 1);

        // chunk-t LDS loads that do NOT depend on the in-flight DMA (overlap the wait)
        const float4 mu = prm4[t * 16 + f4];
        const float4 dv = prm4[256 + t * 16 + f4];
        const float4 al = prm4[512 + t * 16 + f4];
        float4 gtr[16];
        #pragma unroll
        for (int r = 0; r < 16; ++r) gtr[r] = gt4[r * 256 + t * 16 + f4];

        if (t + 1 < 16) asm volatile("s_waitcnt vmcnt(4)" ::: "memory");
        else            asm volatile("s_waitcnt vmcnt(0)" ::: "memory");
        __builtin_amdgcn_sched_barrier(0);

        const float4* cb = (const float4*)&cbuf[t & 1][wave][0][0];
        #pragma unroll
        for (int k = 0; k < 4; ++k) {
            const int rl = slot * 4 + k;
            const float4 cv = cb[rl * 16 + (f4 ^ rl)];
            const float d0 = cv.x - mu.x, d1 = cv.y - mu.y, d2 = cv.z - mu.z, d3 = cv.w - mu.w;
            md[k] = fmaf(d0 * dv.x, d0, md[k]); md[k] = fmaf(d1 * dv.y, d1, md[k]);
            md[k] = fmaf(d2 * dv.z, d2, md[k]); md[k] = fmaf(d3 * dv.w, d3, md[k]);
            aa[k] = fmaf(al.x, d0, aa[k]); aa[k] = fmaf(al.y, d1, aa[k]);
            aa[k] = fmaf(al.z, d2, aa[k]); aa[k] = fmaf(al.w, d3, aa[k]);
            #pragma unroll
            for (int r = 0; r < 16; ++r) {
                g[k][r] = fmaf(gtr[r].x, d0, g[k][r]);
                g[k][r] = fmaf(gtr[r].y, d1, g[k][r]);
                g[k][r] = fmaf(gtr[r].z, d2, g[k][r]);
                g[k][r] = fmaf(gtr[r].w, d3, g[k][r]);
            }
        }
    }

    // ---- epilogue: per row k, fold g[k][0..15] across the 16-lane f4-group
    float w_[4];
    #pragma unroll
    for (int k = 0; k < 4; ++k) {
        float v[16];
        #pragma unroll
        for (int r = 0; r < 16; ++r) v[r] = g[k][r];
        #pragma unroll
        for (int s4 = 0; s4 < 4; ++s4) {
            const int m = 1 << s4;
            const int half = 8 >> s4;
            const bool up = (lane & m) != 0;
            #pragma unroll
            for (int ii = 0; ii < half; ++ii) {
                float x0 = v[2 * ii], x1 = v[2 * ii + 1];
                float y0 = __shfl_xor(x0, m, 64);
                float y1 = __shfl_xor(x1, m, 64);
                v[ii] = up ? (x1 + y1) : (x0 + y0);
            }
        }
        w_[k] = v[0];     // w for row slot*4+k, component r = f4
    }

    // md/aa reduce within 16-lane group
    #pragma unroll
    for (int m = 1; m < 16; m <<= 1) {
        #pragma unroll
        for (int k = 0; k < 4; ++k) {
            md[k] += __shfl_xor(md[k], m, 64);
            aa[k] += __shfl_xor(aa[k], m, 64);
        }
    }

    // corr_k = w^T Minv w (Minv symmetric: read [s][f4] = [f4][s], conflict-free)
    const int base16 = lane & 48;
    float corr[4];
    #pragma unroll
    for (int k = 0; k < 4; ++k) {
        float y = 0.f;
        #pragma unroll
        for (int s = 0; s < 16; ++s)
            y = fmaf(minv_s[s * 16 + f4], __shfl(w_[k], base16 + s, 64), y);
        float c = w_[k] * y;
        c += __shfl_xor(c, 1, 64);
        c += __shfl_xor(c, 2, 64);
        c += __shfl_xor(c, 4, 64);
        c += __shfl_xor(c, 8, 64);
        corr[k] = c;
    }

    if (f4 == 0) {
        const float ld = ws[WS_LOGDET + b];
        #pragma unroll
        for (int k = 0; k < 4; ++k) {
            const float lsig = fminf(aa[k], 0.f) - log1pf(expf(-fabsf(aa[k])));
            out[(size_t)b * NN + n0 + wave * 16 + slot * 4 + k] =
                -0.5f * (md[k] - corr[k] + ld) + lsig;
        }
    }
}

extern "C" void kernel_launch(void* const* d_in, const int* in_sizes, int n_in,
                              void* d_out, int out_size, void* d_ws, size_t ws_size,
                              hipStream_t stream)
{
    const float* qe   = (const float*)d_in[0];
    const float* ctx  = (const float*)d_in[1];
    const float* W1   = (const float*)d_in[2];
    const float* b1   = (const float*)d_in[3];
    const float* Wd   = (const float*)d_in[4];
    const float* bd   = (const float*)d_in[5];
    const float* WL   = (const float*)d_in[6];
    const float* bL   = (const float*)d_in[7];
    const float* Wdel = (const float*)d_in[8];
    const float* bdel = (const float*)d_in[9];
    const float* Wa   = (const float*)d_in[10];
    const float* ba   = (const float*)d_in[11];
    float* out = (float*)d_out;
    float* ws  = (float*)d_ws;

    ka1_h<<<128, 256, 0, stream>>>(qe, W1, ws);
    ka2_heads<<<304, 256, 0, stream>>>(qe, b1, Wd, bd, WL, bL, Wdel, bdel, Wa, ba, ws);
    kg_gt<<<512, 256, 0, stream>>>(ws);
    kMGJ<<<8, 1024, 0, stream>>>(ws);
    kc_main<<<256, 512, 0, stream>>>(ctx, ws, out);
}